// Round 5
// baseline (228.616 us; speedup 1.0000x reference)
//
#include <hip/hip_runtime.h>

typedef __attribute__((ext_vector_type(8))) short bf16x8;   // 8 bf16 (4 VGPRs)
typedef __attribute__((ext_vector_type(4))) float f32x4;    // MFMA acc / load quad

#define KSPLIT_V 24
#define KSTEPS_V 90    // 24 * 90 * 32 = 69120
#define KSPLIT_A 4
#define KSTEPS_A 10    // 4 * 10 * 32 = 1280

// pack two f32 -> one dword of 2 bf16 (RNE), single HW instruction
__device__ __forceinline__ unsigned int pk2(float a, float b) {
    unsigned int r;
    asm("v_cvt_pk_bf16_f32 %0, %1, %2" : "=v"(r) : "v"(a), "v"(b));
    return r;
}
// pinned (volatile) global loads: issue point fixed, dest regs forced live
__device__ __forceinline__ void gl4(f32x4& d, const float* p) {
    asm volatile("global_load_dwordx4 %0, %1, off" : "=&v"(d) : "v"(p));
}
__device__ __forceinline__ void gl4o(f32x4& d, const float* p) {   // +16B
    asm volatile("global_load_dwordx4 %0, %1, off offset:16" : "=&v"(d) : "v"(p));
}
__device__ __forceinline__ void gl1(float& d, const float* p) {
    asm volatile("global_load_dword %0, %1, off" : "=&v"(d) : "v"(p));
}
__device__ __forceinline__ void gl1o(float& d, const float* p) {   // +2048B (= 1 k-row)
    asm volatile("global_load_dword %0, %1, off offset:2048" : "=&v"(d) : "v"(p));
}

// ---------------------------------------------------------------------------
// MODE 0: visual GEMM  (A = cropped visual, B = W_v k-major), partials out
// MODE 1: audio  GEMM  (A = audio,          B = W_a k-major), partials out
// MODE 2: similarity   (A = Anorm rows, B = Vnorm rows), exp/rowsum/diag out
// Tile 64x64, BK=32, 256 threads = 4 waves (2x2 of 32x32).
// Explicit 1-deep pipeline: asm loads at top of step t for t+1, counted vmcnt.
// ---------------------------------------------------------------------------
template<int MODE>
__global__ __launch_bounds__(256, 6) void mm_kernel(
    const float* __restrict__ s1, const float* __restrict__ s2,
    const float* __restrict__ Bsrc, float* __restrict__ outp,
    float* __restrict__ den, float* __restrict__ num)
{
    __shared__ uint4 As[2][256];   // [buf][kb(4)][row(64)] 8-k bf16 units, XOR swizzle
    __shared__ uint4 Bs[2][256];   // [buf][kb(4)][col(64)]

    const int tid = threadIdx.x;
    const int blk = blockIdx.x;

    int m0, n0, k0, nsteps, z = 0;
    if (MODE == 0) {
        // XCD-chunked: xcd gets 192 consecutive lin = 3 whole z-slices
        const int lin = (blk & 7) * 192 + (blk >> 3);
        z  = lin >> 6;
        const int rem = lin & 63;
        m0 = (rem >> 3) * 64;
        n0 = (rem & 7) * 64;
        k0 = z * (KSTEPS_V * 32);
        nsteps = KSTEPS_V;
    } else if (MODE == 1) {
        z  = blk >> 6;
        m0 = ((blk >> 3) & 7) * 64;
        n0 = (blk & 7) * 64;
        k0 = z * (KSTEPS_A * 32);
        nsteps = KSTEPS_A;
    } else {
        m0 = (blk >> 3) * 64;
        n0 = (blk & 7) * 64;
        k0 = 0;
        nsteps = 16;                // K = 512
    }
    if (MODE != 2) outp += (size_t)z * (512 * 512);

    const int ROWSTR = (MODE == 0) ? 138240 : (MODE == 1 ? 1280 : 512);

    // --- staging thread mapping (one 8-k bf16 unit per thread per operand)
    const int a_row = tid >> 2;        // 0..63
    const int a_kb  = tid & 3;         // 0..3
    const int b_col = tid & 63;        // 0..63
    const int b_kb  = tid >> 6;        // 0..3
    const int a_u = (a_kb * 64 + a_row) ^ (a_kb << 1);
    const int b_u = (b_kb * 64 + b_col) ^ (b_kb << 1);

    const int grow = m0 + a_row;
    const float* abase = (grow < 256) ? (s1 + (size_t)grow * ROWSTR)
                                      : (s2 + (size_t)(grow - 256) * ROWSTR);
    // crop mapping (MODE 0): within a 4608-k chunk the source is CONTIGUOUS:
    // off = c*46080 + t*9216 + 4608 + (k - chunk*4608)
    int aoff, jj = 0, kglob = k0;
    if (MODE == 0) {
        const int ph = k0 / 4608;
        jj = k0 - ph * 4608;
        const int c = ph % 3, t = ph / 3;
        aoff = c * 46080 + t * 9216 + 4608 + jj + a_kb * 8;
    } else {
        aoff = k0 + a_kb * 8;
    }

    // B pointers
    const float* bptr = Bsrc;                       // MODE 2
    const float* bp0 = Bsrc; const float* bp1 = Bsrc;
    const float* bp2 = Bsrc; const float* bp3 = Bsrc;
    if (MODE == 2) {
        bptr = Bsrc + (size_t)(n0 + b_col) * 512 + b_kb * 8;
    } else {
        bp0 = Bsrc + (size_t)(k0 + b_kb * 8) * 512 + n0 + b_col;
        bp1 = bp0 + 1024;           // +2 k-rows
        bp2 = bp0 + 2048;
        bp3 = bp0 + 3072;
    }

    // --- wave tiling: 4 waves = 2x2 of 32x32
    const int lane = tid & 63;
    const int wid  = tid >> 6;
    const int wrow = (wid >> 1) * 32;
    const int wcol = (wid & 1) * 32;
    const int l15  = lane & 15;
    const int lk   = lane >> 4;

    int ra[2], rb[2];
    #pragma unroll
    for (int m = 0; m < 2; ++m) ra[m] = (lk * 64 + wrow + m * 16 + l15) ^ (lk << 1);
    #pragma unroll
    for (int n = 0; n < 2; ++n) rb[n] = (lk * 64 + wcol + n * 16 + l15) ^ (lk << 1);

    f32x4 acc[2][2];
    #pragma unroll
    for (int m = 0; m < 2; ++m)
        #pragma unroll
        for (int n = 0; n < 2; ++n) acc[m][n] = f32x4{0.f, 0.f, 0.f, 0.f};

    // --- pipeline register sets (ping-pong)
    f32x4 A0c, A1c, A0n, A1n;
    f32x4 B0c, B1c, B0n, B1n;          // MODE 2
    float bc[8], bn[8];                // MODE 0/1

    auto ISSUE = [&](f32x4& X0, f32x4& X1, float* bb, f32x4& Y0, f32x4& Y1) {
        const float* ap = abase + aoff;
        gl4(X0, ap); gl4o(X1, ap);
        if constexpr (MODE == 2) {
            gl4(Y0, bptr); gl4o(Y1, bptr);
        } else {
            gl1(bb[0], bp0); gl1o(bb[1], bp0);
            gl1(bb[2], bp1); gl1o(bb[3], bp1);
            gl1(bb[4], bp2); gl1o(bb[5], bp2);
            gl1(bb[6], bp3); gl1o(bb[7], bp3);
        }
    };
    auto ADV = [&]() {
        if constexpr (MODE == 0) {
            kglob += 32; aoff += 32; jj += 32;
            if (jj == 4608) {               // chunk boundary (rare, uniform)
                jj = 0;
                const int ph = kglob / 4608;
                const int c = ph % 3, t = ph / 3;
                aoff = c * 46080 + t * 9216 + 4608 + a_kb * 8;
            }
        } else {
            aoff += 32;
        }
        if constexpr (MODE == 2) bptr += 32;
        else { bp0 += 16384; bp1 += 16384; bp2 += 16384; bp3 += 16384; }
    };
    auto WAITN = [&]() {  // leave newest batch in flight, drain older
        if constexpr (MODE == 2) asm volatile("s_waitcnt vmcnt(4)" ::: "memory");
        else                     asm volatile("s_waitcnt vmcnt(10)" ::: "memory");
        __builtin_amdgcn_sched_barrier(0);
    };
    auto WAIT0 = [&]() {
        asm volatile("s_waitcnt vmcnt(0)" ::: "memory");
        __builtin_amdgcn_sched_barrier(0);
    };
    auto PACK = [&](int buf, f32x4& X0, f32x4& X1, float* bb, f32x4& Y0, f32x4& Y1) {
        uint4 pa;
        pa.x = pk2(X0.x, X0.y); pa.y = pk2(X0.z, X0.w);
        pa.z = pk2(X1.x, X1.y); pa.w = pk2(X1.z, X1.w);
        As[buf][a_u] = pa;
        uint4 pb;
        if constexpr (MODE == 2) {
            pb.x = pk2(Y0.x, Y0.y); pb.y = pk2(Y0.z, Y0.w);
            pb.z = pk2(Y1.x, Y1.y); pb.w = pk2(Y1.z, Y1.w);
        } else {
            pb.x = pk2(bb[0], bb[1]); pb.y = pk2(bb[2], bb[3]);
            pb.z = pk2(bb[4], bb[5]); pb.w = pk2(bb[6], bb[7]);
        }
        Bs[buf][b_u] = pb;
    };
    auto MM = [&](int buf) {
        bf16x8 af[2], bfr[2];
        #pragma unroll
        for (int m = 0; m < 2; ++m) af[m] = __builtin_bit_cast(bf16x8, As[buf][ra[m]]);
        #pragma unroll
        for (int n = 0; n < 2; ++n) bfr[n] = __builtin_bit_cast(bf16x8, Bs[buf][rb[n]]);
        #pragma unroll
        for (int m = 0; m < 2; ++m)
            #pragma unroll
            for (int n = 0; n < 2; ++n)
                acc[m][n] = __builtin_amdgcn_mfma_f32_16x16x32_bf16(af[m], bfr[n], acc[m][n], 0, 0, 0);
    };

    // --- prologue: issue step-0 loads
    ISSUE(A0c, A1c, bc, B0c, B1c);

    // nsteps is even for all modes (90 / 10 / 16)
    for (int ks = 0; ks < nsteps; ks += 2) {
        // even step: consume c-set, prefetch n-set
        ADV(); ISSUE(A0n, A1n, bn, B0n, B1n);
        WAITN();
        PACK(0, A0c, A1c, bc, B0c, B1c);
        __syncthreads();
        MM(0);
        // odd step: consume n-set, prefetch c-set
        if (ks + 2 < nsteps) { ADV(); ISSUE(A0c, A1c, bc, B0c, B1c); WAITN(); }
        else                 { WAIT0(); }
        PACK(1, A0n, A1n, bn, B0n, B1n);
        __syncthreads();
        MM(1);
    }

    // --- epilogue.  C/D layout: col = lane&15, row = (lane>>4)*4 + reg
    if (MODE != 2) {
        #pragma unroll
        for (int m = 0; m < 2; ++m)
            #pragma unroll
            for (int n = 0; n < 2; ++n) {
                const int col = n0 + wcol + n * 16 + l15;
                #pragma unroll
                for (int r = 0; r < 4; ++r) {
                    const int row = m0 + wrow + m * 16 + lk * 4 + r;
                    outp[(size_t)row * 512 + col] = acc[m][n][r];
                }
            }
    } else {
        // S[row,col] = a_row . v_col ; den[row&255] += sum_col exp(S);
        // diagonal-family terms into num[row&255]
        #pragma unroll
        for (int m = 0; m < 2; ++m) {
            float rs[4] = {0.f, 0.f, 0.f, 0.f};
            #pragma unroll
            for (int n = 0; n < 2; ++n) {
                const int col = n0 + wcol + n * 16 + l15;
                #pragma unroll
                for (int r = 0; r < 4; ++r) {
                    const int row = m0 + wrow + m * 16 + lk * 4 + r;
                    const float e = __expf(acc[m][n][r]);
                    rs[r] += e;
                    if (((row - col) & 255) == 0) atomicAdd(num + (row & 255), e);
                }
            }
            #pragma unroll
            for (int r = 0; r < 4; ++r) {
                float v = rs[r];
                v += __shfl_xor(v, 1);
                v += __shfl_xor(v, 2);
                v += __shfl_xor(v, 4);
                v += __shfl_xor(v, 8);
                if (l15 == 0) {
                    const int row = m0 + wrow + m * 16 + lk * 4 + r;
                    atomicAdd(den + (row & 255), v);
                }
            }
        }
    }
}

// ---------- reduce split-K partials + row L2 normalization ----------
__global__ __launch_bounds__(256) void norm_kernel(
    const float* __restrict__ partA, const float* __restrict__ partV,
    float* __restrict__ Aout, float* __restrict__ Vout)
{
    const int row = blockIdx.x;          // 0..1023
    const int tid = threadIdx.x;
    const bool isV = row >= 512;
    const int r = isV ? (row - 512) : row;
    const int c0 = tid, c1 = tid + 256;

    float v0 = 0.f, v1 = 0.f;
    if (isV) {
        #pragma unroll
        for (int zz = 0; zz < KSPLIT_V; ++zz) {
            const float* p = partV + (size_t)zz * 262144 + (size_t)r * 512;
            v0 += p[c0]; v1 += p[c1];
        }
    } else {
        #pragma unroll
        for (int zz = 0; zz < KSPLIT_A; ++zz) {
            const float* p = partA + (size_t)zz * 262144 + (size_t)r * 512;
            v0 += p[c0]; v1 += p[c1];
        }
    }

    float ss = v0 * v0 + v1 * v1;
    #pragma unroll
    for (int off = 32; off > 0; off >>= 1) ss += __shfl_down(ss, off);
    __shared__ float sbuf[4];
    if ((tid & 63) == 0) sbuf[tid >> 6] = ss;
    __syncthreads();
    const float total = sbuf[0] + sbuf[1] + sbuf[2] + sbuf[3];
    const float inv = 1.f / fmaxf(sqrtf(total), 1e-12f);

    float* outp = (isV ? Vout : Aout) + (size_t)r * 512;
    outp[c0] = v0 * inv;
    outp[c1] = v1 * inv;
}

// ---------- zero den/num accumulators ----------
__global__ __launch_bounds__(512) void zero_kernel(float* __restrict__ p) {
    p[threadIdx.x] = 0.f;
}

// ---------- a1.a2 and v1.v2 dots -> num += exp(dot) ----------
__global__ __launch_bounds__(256) void dots_kernel(
    const float* __restrict__ A, const float* __restrict__ V,
    float* __restrict__ num)
{
    const int b = blockIdx.x;            // 0..511
    const int i = b & 255;
    const float* X = (b < 256) ? A : V;
    const float* x = X + (size_t)i * 512;
    const float* y = X + (size_t)(i + 256) * 512;
    const int tid = threadIdx.x;
    float d = x[tid] * y[tid] + x[tid + 256] * y[tid + 256];
    #pragma unroll
    for (int off = 32; off > 0; off >>= 1) d += __shfl_down(d, off);
    __shared__ float sbuf[4];
    if ((tid & 63) == 0) sbuf[tid >> 6] = d;
    __syncthreads();
    if (tid == 0) atomicAdd(num + i, __expf(sbuf[0] + sbuf[1] + sbuf[2] + sbuf[3]));
}

// ---------- final: loss = mean(log den - log num) ----------
__global__ __launch_bounds__(256) void final_kernel(
    const float* __restrict__ den, const float* __restrict__ num,
    float* __restrict__ out)
{
    const int tid = threadIdx.x;
    float v = logf(den[tid]) - logf(num[tid]);
    #pragma unroll
    for (int off = 32; off > 0; off >>= 1) v += __shfl_down(v, off);
    __shared__ float sbuf[4];
    if ((tid & 63) == 0) sbuf[tid >> 6] = v;
    __syncthreads();
    if (tid == 0) out[0] = (sbuf[0] + sbuf[1] + sbuf[2] + sbuf[3]) * (1.f / 256.f);
}

// ---------- launch ----------
extern "C" void kernel_launch(void* const* d_in, const int* in_sizes, int n_in,
                              void* d_out, int out_size, void* d_ws, size_t ws_size,
                              hipStream_t stream)
{
    (void)in_sizes; (void)n_in; (void)out_size; (void)ws_size;
    const float* a_1 = (const float*)d_in[0];
    const float* v_1 = (const float*)d_in[1];
    const float* a_2 = (const float*)d_in[2];
    const float* v_2 = (const float*)d_in[3];
    const float* W_a = (const float*)d_in[4];
    const float* W_v = (const float*)d_in[5];
    float* out = (float*)d_out;

    float* ws      = (float*)d_ws;
    float* partV   = ws;                                     // 24 MB
    float* partA   = partV + (size_t)KSPLIT_V * 262144;      // 4 MB
    float* Anorm   = partA + (size_t)KSPLIT_A * 262144;      // 1 MB
    float* Vnorm   = Anorm + 262144;                         // 1 MB
    float* den     = Vnorm + 262144;                         // 256 f
    float* num     = den + 256;                              // 256 f

    zero_kernel<<<1, 512, 0, stream>>>(den);  // zeros den[256] + num[256]
    mm_kernel<0><<<KSPLIT_V * 64, 256, 0, stream>>>(v_1, v_2, W_v, partV, nullptr, nullptr);
    mm_kernel<1><<<KSPLIT_A * 64, 256, 0, stream>>>(a_1, a_2, W_a, partA, nullptr, nullptr);
    norm_kernel<<<1024, 256, 0, stream>>>(partA, partV, Anorm, Vnorm);
    mm_kernel<2><<<64, 256, 0, stream>>>(Anorm, Anorm + 256 * 512, Vnorm, nullptr, den, num);
    dots_kernel<<<512, 256, 0, stream>>>(Anorm, Vnorm, num);
    final_kernel<<<1, 256, 0, stream>>>(den, num, out);
}

// Round 6
// 199.822 us; speedup vs baseline: 1.1441x; 1.1441x over previous
//
#include <hip/hip_runtime.h>

typedef __attribute__((ext_vector_type(8))) short bf16x8;   // 8 bf16 (4 VGPRs)
typedef __attribute__((ext_vector_type(4))) float f32x4;    // MFMA accumulator

// pack two f32 -> one dword of 2 bf16 (RNE), single HW instruction
__device__ __forceinline__ unsigned int pk2(float a, float b) {
    unsigned int r;
    asm("v_cvt_pk_bf16_f32 %0, %1, %2" : "=v"(r) : "v"(a), "v"(b));
    return r;
}

// global -> LDS direct copy, 16B per lane. LDS dest = wave-uniform base + lane*16.
__device__ __forceinline__ void gll16(void* lds, const void* g) {
    __builtin_amdgcn_global_load_lds(
        (__attribute__((address_space(1))) void*)(uintptr_t)g,
        (__attribute__((address_space(3))) void*)(uint32_t)(uintptr_t)lds,
        16, 0, 0);
}

// ---------------------------------------------------------------------------
// conv_fused: one streaming kernel doing all f32 -> bf16 conversions.
// blocks [0,8640): W_v [69120][512] -> Wt bf16 [512][69120]  (transpose)
// blocks [8640,8800): W_a [1280][512] -> Wat bf16 [512][1280] (transpose)
// blocks [8800,16480): cropped visual -> Av bf16 [512][69120]
// blocks [16480,17120): audio -> Aa bf16 [512][1280]
// ---------------------------------------------------------------------------
__global__ __launch_bounds__(256) void conv_fused(
    const float* __restrict__ v_1, const float* __restrict__ v_2,
    const float* __restrict__ a_1, const float* __restrict__ a_2,
    const float* __restrict__ W_v, const float* __restrict__ W_a,
    unsigned short* __restrict__ Av, unsigned short* __restrict__ Wt,
    unsigned short* __restrict__ Aa, unsigned short* __restrict__ Wat,
    int doAv)
{
    __shared__ float T[64][65];
    const int tid = threadIdx.x;
    const int b = blockIdx.x;

    if (b < 8800) {
        // ---- transpose W (visual: 1080 k-tiles, audio: 20 k-tiles) ----
        const float* src; unsigned short* dst; int K, kt, nt;
        if (b < 8640) { src = W_v; dst = Wt;  K = 69120; kt = b >> 3; nt = b & 7; }
        else          { src = W_a; dst = Wat; K = 1280;  kt = (b - 8640) >> 3; nt = (b - 8640) & 7; }
        const int k0 = kt * 64, n0 = nt * 64;
        #pragma unroll
        for (int i = 0; i < 4; ++i) {
            const int kr = i * 16 + (tid >> 4);
            const int c4 = tid & 15;
            const float4 f = *(const float4*)(src + (size_t)(k0 + kr) * 512 + n0 + c4 * 4);
            T[c4 * 4 + 0][kr] = f.x; T[c4 * 4 + 1][kr] = f.y;
            T[c4 * 4 + 2][kr] = f.z; T[c4 * 4 + 3][kr] = f.w;
        }
        __syncthreads();
        #pragma unroll
        for (int j = 0; j < 2; ++j) {
            const int id = j * 256 + tid;
            const int nl = id >> 3, u = id & 7;
            float v[8];
            #pragma unroll
            for (int kk = 0; kk < 8; ++kk) v[kk] = T[nl][u * 8 + kk];
            uint4 o;
            o.x = pk2(v[0], v[1]); o.y = pk2(v[2], v[3]);
            o.z = pk2(v[4], v[5]); o.w = pk2(v[6], v[7]);
            *(uint4*)(dst + (size_t)(n0 + nl) * K + k0 + u * 8) = o;
        }
    } else if (b < 16480) {
        // ---- visual crop stream: block = (row, chunk p), 4608 f32 ----
        if (!doAv) return;
        const int bb = b - 8800;
        const int r = bb / 15, p = bb - r * 15;
        const float* srcb = (r < 256) ? (v_1 + (size_t)r * 138240)
                                      : (v_2 + (size_t)(r - 256) * 138240);
        const int c = p % 3, t9 = p / 3;
        const float* src = srcb + c * 46080 + t9 * 9216 + 4608;
        unsigned short* dst = Av + (size_t)r * 69120 + p * 4608;
        #pragma unroll
        for (int it = 0; it < 5; ++it) {
            const int u = it * 256 + tid;
            if (u < 1152) {
                const float4 f = *(const float4*)(src + u * 4);
                uint2 o; o.x = pk2(f.x, f.y); o.y = pk2(f.z, f.w);
                *(uint2*)(dst + u * 4) = o;
            }
        }
    } else {
        // ---- audio stream: 512 rows x 1280 ----
        const int idx4 = (b - 16480) * 256 + tid;     // float4 index, < 163840
        const int row = idx4 / 320;
        const int col4 = idx4 - row * 320;
        const float* src = (row < 256) ? (a_1 + (size_t)row * 1280)
                                       : (a_2 + (size_t)(row - 256) * 1280);
        const float4 f = *(const float4*)(src + col4 * 4);
        uint2 o; o.x = pk2(f.x, f.y); o.y = pk2(f.z, f.w);
        *(uint2*)(Aa + (size_t)idx4 * 4) = o;
    }
}

// ---------------------------------------------------------------------------
// GEMM: C[512,512] = A[512,K] * B^T  with A,B row-major-K bf16.
// Tile 128x128, BK=64, 256 threads = 4 waves (2x2 of 64x64). Split-K partials.
// Staging: global_load_lds 16B/lane, XOR swizzle via pre-swizzled global src.
// AMODE 0: A from bf16 Av/Aa.  AMODE 1: A from f32 visual (crop), reg-staged.
// ---------------------------------------------------------------------------
template<int AMODE>
__global__ __launch_bounds__(256, 3) void gemm_kernel(
    const unsigned short* __restrict__ Abf,
    const float* __restrict__ s1, const float* __restrict__ s2,
    const unsigned short* __restrict__ Bt,
    float* __restrict__ part, int K, int ksteps)
{
    __shared__ uint4 As[1024];   // [128 rows][8 units of 8 bf16], unit ^= row&7
    __shared__ uint4 Bs[1024];   // [128 cols][8 units]

    const int tid = threadIdx.x;
    const int blk = blockIdx.x;
    const int nwg = gridDim.x;
    const int cpx = nwg >> 3;                       // blocks per XCD
    const int lin = (blk & 7) * cpx + (blk >> 3);   // XCD-chunked swizzle
    const int z  = lin >> 4;
    const int mn = lin & 15;
    const int m0 = (mn >> 2) * 128;
    const int n0 = (mn & 3) * 128;
    const int k0 = z * ksteps * 64;
    part += (size_t)z * 262144;

    const int wid = tid >> 6, lane = tid & 63;
    const int l15 = lane & 15, lk = lane >> 4;
    const int wm = (wid >> 1) * 64, wn = (wid & 1) * 64;

    // fragment LDS units (constant over K loop)
    int ua[2][4], ub[2][4];
    #pragma unroll
    for (int kh = 0; kh < 2; ++kh) {
        #pragma unroll
        for (int mi = 0; mi < 4; ++mi) {
            const int row = wm + mi * 16 + l15;
            ua[kh][mi] = row * 8 + ((kh * 4 + lk) ^ (row & 7));
        }
        #pragma unroll
        for (int ni = 0; ni < 4; ++ni) {
            const int nn = wn + ni * 16 + l15;
            ub[kh][ni] = nn * 8 + ((kh * 4 + lk) ^ (nn & 7));
        }
    }

    // staging sources (advance by 64 elems per step)
    const unsigned short* bsrc[4];
    const unsigned short* asrc[4];
    #pragma unroll
    for (int i = 0; i < 4; ++i) {
        const int u = i * 256 + tid;
        const int rw = u >> 3, c = u & 7;
        bsrc[i] = Bt + (size_t)(n0 + rw) * K + k0 + ((c ^ (rw & 7)) * 8);
        if (AMODE == 0)
            asrc[i] = Abf + (size_t)(m0 + rw) * K + k0 + ((c ^ (rw & 7)) * 8);
    }
    // AMODE 1: f32 reg staging, thread covers row=tid>>1, 4 k-chunks
    const int a_row = tid >> 1;
    const float* abase = nullptr;
    if (AMODE == 1) {
        const int grow = m0 + a_row;
        abase = (grow < 256) ? (s1 + (size_t)grow * 138240)
                             : (s2 + (size_t)(grow - 256) * 138240);
    }

    f32x4 acc[4][4];
    #pragma unroll
    for (int mi = 0; mi < 4; ++mi)
        #pragma unroll
        for (int ni = 0; ni < 4; ++ni) acc[mi][ni] = f32x4{0.f, 0.f, 0.f, 0.f};

    int kc = k0;
    for (int ks = 0; ks < ksteps; ++ks) {
        // ---- stage tiles ----
        #pragma unroll
        for (int i = 0; i < 4; ++i)
            gll16(Bs + i * 256 + wid * 64, bsrc[i]);
        if (AMODE == 0) {
            #pragma unroll
            for (int i = 0; i < 4; ++i)
                gll16(As + i * 256 + wid * 64, asrc[i]);
        } else {
            #pragma unroll
            for (int x4 = 0; x4 < 4; ++x4) {
                const int x = (tid & 1) * 4 + x4;
                const int kg = kc + x * 8;
                const int p = kg / 4608;
                const int j = kg - p * 4608;
                const int c3 = p % 3, t9 = p / 3;
                const float* ap = abase + c3 * 46080 + t9 * 9216 + 4608 + j;
                const float4 f0 = *(const float4*)ap;
                const float4 f1 = *(const float4*)(ap + 4);
                uint4 pa;
                pa.x = pk2(f0.x, f0.y); pa.y = pk2(f0.z, f0.w);
                pa.z = pk2(f1.x, f1.y); pa.w = pk2(f1.z, f1.w);
                As[a_row * 8 + (x ^ (a_row & 7))] = pa;
            }
        }
        __syncthreads();

        // ---- compute ----
        #pragma unroll
        for (int kh = 0; kh < 2; ++kh) {
            bf16x8 af[4], bfr[4];
            #pragma unroll
            for (int mi = 0; mi < 4; ++mi) af[mi] = __builtin_bit_cast(bf16x8, As[ua[kh][mi]]);
            #pragma unroll
            for (int ni = 0; ni < 4; ++ni) bfr[ni] = __builtin_bit_cast(bf16x8, Bs[ub[kh][ni]]);
            #pragma unroll
            for (int mi = 0; mi < 4; ++mi)
                #pragma unroll
                for (int ni = 0; ni < 4; ++ni)
                    acc[mi][ni] = __builtin_amdgcn_mfma_f32_16x16x32_bf16(af[mi], bfr[ni], acc[mi][ni], 0, 0, 0);
        }
        __syncthreads();

        // ---- advance ----
        kc += 64;
        #pragma unroll
        for (int i = 0; i < 4; ++i) bsrc[i] += 64;
        if (AMODE == 0) {
            #pragma unroll
            for (int i = 0; i < 4; ++i) asrc[i] += 64;
        }
    }

    // ---- epilogue: fp32 partials. C/D: col = lane&15, row = (lane>>4)*4+r ----
    #pragma unroll
    for (int mi = 0; mi < 4; ++mi)
        #pragma unroll
        for (int ni = 0; ni < 4; ++ni) {
            const int col = n0 + wn + ni * 16 + l15;
            #pragma unroll
            for (int r = 0; r < 4; ++r) {
                const int row = m0 + wm + mi * 16 + lk * 4 + r;
                part[(size_t)row * 512 + col] = acc[mi][ni][r];
            }
        }
}

// ---------- reduce split-K partials + row L2 normalization ----------
__global__ __launch_bounds__(256) void norm_kernel(
    const float* __restrict__ partA, const float* __restrict__ partV,
    float* __restrict__ Aout, float* __restrict__ Vout, int nzV)
{
    const int row = blockIdx.x;          // 0..1023
    const int tid = threadIdx.x;
    const bool isV = row >= 512;
    const int r = isV ? (row - 512) : row;
    const int c0 = tid, c1 = tid + 256;

    float v0 = 0.f, v1 = 0.f;
    if (isV) {
        for (int zz = 0; zz < nzV; ++zz) {
            const float* p = partV + (size_t)zz * 262144 + (size_t)r * 512;
            v0 += p[c0]; v1 += p[c1];
        }
    } else {
        #pragma unroll
        for (int zz = 0; zz < 2; ++zz) {
            const float* p = partA + (size_t)zz * 262144 + (size_t)r * 512;
            v0 += p[c0]; v1 += p[c1];
        }
    }

    float ss = v0 * v0 + v1 * v1;
    #pragma unroll
    for (int off = 32; off > 0; off >>= 1) ss += __shfl_down(ss, off);
    __shared__ float sbuf[4];
    if ((tid & 63) == 0) sbuf[tid >> 6] = ss;
    __syncthreads();
    const float total = sbuf[0] + sbuf[1] + sbuf[2] + sbuf[3];
    const float inv = 1.f / fmaxf(sqrtf(total), 1e-12f);

    float* outp = (isV ? Vout : Aout) + (size_t)r * 512;
    outp[c0] = v0 * inv;
    outp[c1] = v1 * inv;
}

// ---------------------------------------------------------------------------
// similarity kernel: S = Anorm . Vnorm^T (64x64 tiles, f32 in, bf16 MFMA),
// epilogue: den[row&255] += sum_col exp(S); diag-family exp -> num[row&255]
// ---------------------------------------------------------------------------
__global__ __launch_bounds__(256) void sim_kernel(
    const float* __restrict__ A, const float* __restrict__ V,
    float* __restrict__ den, float* __restrict__ num)
{
    __shared__ uint4 As[2][256];
    __shared__ uint4 Bs[2][256];

    const int tid = threadIdx.x;
    const int m0 = (blockIdx.x >> 3) * 64;
    const int n0 = (blockIdx.x & 7) * 64;
    const int nsteps = 16;               // K = 512

    const int a_row = tid >> 2, a_kb = tid & 3;
    const int b_col = tid & 63, b_kb = tid >> 6;
    const int a_u = (a_kb * 64 + a_row) ^ (a_kb << 1);
    const int b_u = (b_kb * 64 + b_col) ^ (b_kb << 1);

    const float* abase = A + (size_t)(m0 + a_row) * 512;
    const float* bptr  = V + (size_t)(n0 + b_col) * 512 + b_kb * 8;
    int aoff = a_kb * 8;

    const int lane = tid & 63, wid = tid >> 6;
    const int wrow = (wid >> 1) * 32, wcol = (wid & 1) * 32;
    const int l15 = lane & 15, lk = lane >> 4;

    int ra[2], rb[2];
    #pragma unroll
    for (int m = 0; m < 2; ++m) ra[m] = (lk * 64 + wrow + m * 16 + l15) ^ (lk << 1);
    #pragma unroll
    for (int n = 0; n < 2; ++n) rb[n] = (lk * 64 + wcol + n * 16 + l15) ^ (lk << 1);

    f32x4 acc[2][2];
    #pragma unroll
    for (int m = 0; m < 2; ++m)
        #pragma unroll
        for (int n = 0; n < 2; ++n) acc[m][n] = f32x4{0.f, 0.f, 0.f, 0.f};

    float4 A0 = *(const float4*)(abase + aoff);
    float4 A1 = *(const float4*)(abase + aoff + 4);
    float4 B0 = *(const float4*)bptr;
    float4 B1 = *(const float4*)(bptr + 4);

    for (int ks = 0; ks < nsteps; ++ks) {
        const int cur = ks & 1;
        const bool more = (ks + 1 < nsteps);
        float4 A0n, A1n, B0n, B1n;
        if (more) {
            aoff += 32; bptr += 32;
            A0n = *(const float4*)(abase + aoff);
            A1n = *(const float4*)(abase + aoff + 4);
            B0n = *(const float4*)bptr;
            B1n = *(const float4*)(bptr + 4);
        }
        uint4 pa;
        pa.x = pk2(A0.x, A0.y); pa.y = pk2(A0.z, A0.w);
        pa.z = pk2(A1.x, A1.y); pa.w = pk2(A1.z, A1.w);
        As[cur][a_u] = pa;
        uint4 pb;
        pb.x = pk2(B0.x, B0.y); pb.y = pk2(B0.z, B0.w);
        pb.z = pk2(B1.x, B1.y); pb.w = pk2(B1.z, B1.w);
        Bs[cur][b_u] = pb;
        __syncthreads();

        bf16x8 af[2], bfr[2];
        #pragma unroll
        for (int m = 0; m < 2; ++m) af[m] = __builtin_bit_cast(bf16x8, As[cur][ra[m]]);
        #pragma unroll
        for (int n = 0; n < 2; ++n) bfr[n] = __builtin_bit_cast(bf16x8, Bs[cur][rb[n]]);
        #pragma unroll
        for (int m = 0; m < 2; ++m)
            #pragma unroll
            for (int n = 0; n < 2; ++n)
                acc[m][n] = __builtin_amdgcn_mfma_f32_16x16x32_bf16(af[m], bfr[n], acc[m][n], 0, 0, 0);

        if (more) { A0 = A0n; A1 = A1n; B0 = B0n; B1 = B1n; }
    }

    #pragma unroll
    for (int m = 0; m < 2; ++m) {
        float rs[4] = {0.f, 0.f, 0.f, 0.f};
        #pragma unroll
        for (int n = 0; n < 2; ++n) {
            const int col = n0 + wcol + n * 16 + l15;
            #pragma unroll
            for (int r = 0; r < 4; ++r) {
                const int row = m0 + wrow + m * 16 + lk * 4 + r;
                const float e = __expf(acc[m][n][r]);
                rs[r] += e;
                if (((row - col) & 255) == 0) atomicAdd(num + (row & 255), e);
            }
        }
        #pragma unroll
        for (int r = 0; r < 4; ++r) {
            float v = rs[r];
            v += __shfl_xor(v, 1);
            v += __shfl_xor(v, 2);
            v += __shfl_xor(v, 4);
            v += __shfl_xor(v, 8);
            if (l15 == 0) {
                const int row = m0 + wrow + m * 16 + lk * 4 + r;
                atomicAdd(den + (row & 255), v);
            }
        }
    }
}

// ---------- zero den/num accumulators ----------
__global__ __launch_bounds__(512) void zero_kernel(float* __restrict__ p) {
    p[threadIdx.x] = 0.f;
}

// ---------- a1.a2 and v1.v2 dots -> num += exp(dot) ----------
__global__ __launch_bounds__(256) void dots_kernel(
    const float* __restrict__ A, const float* __restrict__ V,
    float* __restrict__ num)
{
    const int b = blockIdx.x;            // 0..511
    const int i = b & 255;
    const float* X = (b < 256) ? A : V;
    const float* x = X + (size_t)i * 512;
    const float* y = X + (size_t)(i + 256) * 512;
    const int tid = threadIdx.x;
    float d = x[tid] * y[tid] + x[tid + 256] * y[tid + 256];
    #pragma unroll
    for (int off = 32; off > 0; off >>= 1) d += __shfl_down(d, off);
    __shared__ float sbuf[4];
    if ((tid & 63) == 0) sbuf[tid >> 6] = d;
    __syncthreads();
    if (tid == 0) atomicAdd(num + i, __expf(sbuf[0] + sbuf[1] + sbuf[2] + sbuf[3]));
}

// ---------- final: loss = mean(log den - log num) ----------
__global__ __launch_bounds__(256) void final_kernel(
    const float* __restrict__ den, const float* __restrict__ num,
    float* __restrict__ out)
{
    const int tid = threadIdx.x;
    float v = logf(den[tid]) - logf(num[tid]);
    #pragma unroll
    for (int off = 32; off > 0; off >>= 1) v += __shfl_down(v, off);
    __shared__ float sbuf[4];
    if ((tid & 63) == 0) sbuf[tid >> 6] = v;
    __syncthreads();
    if (tid == 0) out[0] = (sbuf[0] + sbuf[1] + sbuf[2] + sbuf[3]) * (1.f / 256.f);
}

// ---------- launch ----------
extern "C" void kernel_launch(void* const* d_in, const int* in_sizes, int n_in,
                              void* d_out, int out_size, void* d_ws, size_t ws_size,
                              hipStream_t stream)
{
    (void)in_sizes; (void)n_in; (void)out_size;
    const float* a_1 = (const float*)d_in[0];
    const float* v_1 = (const float*)d_in[1];
    const float* a_2 = (const float*)d_in[2];
    const float* v_2 = (const float*)d_in[3];
    const float* W_a = (const float*)d_in[4];
    const float* W_v = (const float*)d_in[5];
    float* out = (float*)d_out;

    // ---- workspace tiering ----
    const size_t F_BASE = 512 /*den+num*/ + 2 * 262144 /*norms*/ + 2 * 262144 /*partA*/
                        + 2 * 327680 /*Aa + Wat (bf16 as half-floats)*/ + 17694720 /*Wt*/;
    auto bytes_for = [&](int kv, bool av) {
        return (F_BASE + (size_t)kv * 262144 + (av ? 17694720u : 0u)) * 4;
    };
    int KV; bool AV;
    if      (ws_size >= bytes_for(45, true))  { KV = 45; AV = true;  }
    else if (ws_size >= bytes_for(45, false)) { KV = 45; AV = false; }
    else if (ws_size >= bytes_for(15, false)) { KV = 15; AV = false; }
    else                                      { KV = 8;  AV = false; }
    const int kstepsV = 1080 / KV;            // 24 / 72 / 135

    // ---- carve workspace ----
    float* cur = (float*)d_ws;
    float* den   = cur; cur += 256;
    float* num   = cur; cur += 256;
    float* Anorm = cur; cur += 262144;
    float* Vnorm = cur; cur += 262144;
    float* partA = cur; cur += 2 * 262144;
    unsigned short* Aa  = (unsigned short*)cur; cur += 327680;
    unsigned short* Wat = (unsigned short*)cur; cur += 327680;
    float* partV = cur; cur += (size_t)KV * 262144;
    unsigned short* Wt = (unsigned short*)cur; cur += 17694720;
    unsigned short* Av = (unsigned short*)cur;   // only valid when AV

    zero_kernel<<<1, 512, 0, stream>>>(den);   // zeros den[256]+num[256]

    conv_fused<<<17120, 256, 0, stream>>>(v_1, v_2, a_1, a_2, W_v, W_a,
                                          Av, Wt, Aa, Wat, AV ? 1 : 0);

    if (AV)
        gemm_kernel<0><<<16 * KV, 256, 0, stream>>>(Av, nullptr, nullptr, Wt,
                                                    partV, 69120, kstepsV);
    else
        gemm_kernel<1><<<16 * KV, 256, 0, stream>>>(nullptr, v_1, v_2, Wt,
                                                    partV, 69120, kstepsV);

    gemm_kernel<0><<<32, 256, 0, stream>>>(Aa, nullptr, nullptr, Wat,
                                           partA, 1280, 10);

    norm_kernel<<<1024, 256, 0, stream>>>(partA, partV, Anorm, Vnorm, KV);
    sim_kernel<<<64, 256, 0, stream>>>(Anorm, Vnorm, den, num);
    dots_kernel<<<512, 256, 0, stream>>>(Anorm, Vnorm, num);
    final_kernel<<<1, 256, 0, stream>>>(den, num, out);
}

// Round 7
// 189.309 us; speedup vs baseline: 1.2076x; 1.0555x over previous
//
#include <hip/hip_runtime.h>

typedef __attribute__((ext_vector_type(8))) short bf16x8;   // 8 bf16 (4 VGPRs)
typedef __attribute__((ext_vector_type(4))) float f32x4;    // MFMA accumulator
typedef __attribute__((ext_vector_type(2))) unsigned int u32x2;

#define KSV 45   // split-K visual: 45 * 48 * 32 = 69120
#define KSA 2    // split-K audio:   2 * 20 * 32 = 1280

// pack two f32 -> one dword of 2 bf16 (RNE), single HW instruction
__device__ __forceinline__ unsigned int pk2(float a, float b) {
    unsigned int r;
    asm("v_cvt_pk_bf16_f32 %0, %1, %2" : "=v"(r) : "v"(a), "v"(b));
    return r;
}

// hardware transpose-read: 4 halfwords at lane addr + j*32B (j=0..3)
__device__ __forceinline__ u32x2 tr_lo(unsigned addr) {
    u32x2 r;
    asm volatile("ds_read_b64_tr_b16 %0, %1" : "=v"(r) : "v"(addr));
    return r;
}
__device__ __forceinline__ u32x2 tr_hi(unsigned addr) {   // next k-quad subtile
    u32x2 r;
    asm volatile("ds_read_b64_tr_b16 %0, %1 offset:1024" : "=v"(r) : "v"(addr));
    return r;
}

// ---------------------------------------------------------------------------
// GEMM: C[512,512] = A[512,K] * W[K,512], both f32 in HBM, bf16 MFMA.
// Tile 128x128, BK=32, 256 thr = 4 waves (2x2 of 64x64). Split-K partials.
// A: reg-staged f32->bf16, LDS [128 rows][4 units16B], unit ^= row&3.
// B: reg-staged f32->bf16 from W's k-major rows (contiguous loads!), LDS
//    subtiled [kq(8)][cq(8)][4][16] bf16; fragments via ds_read_b64_tr_b16.
// CROP=1: A rows are cropped visual (stride 138240); CROP=0: audio (1280).
// ---------------------------------------------------------------------------
template<int CROP>
__global__ __launch_bounds__(256, 2) void gemm_kernel(
    const float* __restrict__ s1, const float* __restrict__ s2,
    const float* __restrict__ W, float* __restrict__ part, int ksteps)
{
    __shared__ uint4 As[512];   // 8 KB
    __shared__ uint4 Bs[512];   // 8 KB

    const int tid = threadIdx.x;
    const int blk = blockIdx.x;
    const int cpx = gridDim.x >> 3;
    const int lin = (blk & 7) * cpx + (blk >> 3);   // XCD-chunked swizzle
    const int z  = lin >> 4;
    const int mn = lin & 15;
    const int m0 = (mn >> 2) * 128;
    const int n0 = (mn & 3) * 128;
    const int k0 = z * ksteps * 32;
    part += (size_t)z * 262144;

    // ---- A staging map: thread -> (row, 16-k half)
    const int a_row = tid >> 1;                 // 0..127
    const int a_off = (tid & 1) << 4;           // k offset 0/16
    const int grow  = m0 + a_row;
    const int ROWSTR = CROP ? 138240 : 1280;
    const float* abase = (grow < 256) ? s1 + (size_t)grow * ROWSTR
                                      : s2 + (size_t)(grow - 256) * ROWSTR;
    const int a_u0 = a_row * 4 + (((tid & 1) * 2 + 0) ^ (a_row & 3));
    const int a_u1 = a_row * 4 + (((tid & 1) * 2 + 1) ^ (a_row & 3));

    // ---- B staging map: thread -> (k-row, 16-col group); contiguous reads
    const int b_k = tid >> 3;                   // 0..31
    const int b_g = tid & 7;                    // cols 16g..16g+15
    const float* bbase = W + (size_t)b_k * 512 + b_g * 16;
    // uint4 index: kq*64 + cq*8 + r*2 + h   (byte = kq*1024+cq*128+r*32+h*16)
    const int b_u0 = (b_k >> 2) * 64 + b_g * 8 + (b_k & 3) * 2;

    // ---- wave / fragment map
    const int lane = tid & 63;
    const int wid  = tid >> 6;
    const int l15  = lane & 15;
    const int lk   = lane >> 4;
    const int wm = (wid >> 1) * 64;
    const int wn = (wid & 1) * 64;

    int ua[4];
    #pragma unroll
    for (int mi = 0; mi < 4; ++mi) {
        const int row = wm + mi * 16 + l15;
        ua[mi] = row * 4 + (lk ^ (row & 3));
    }
    const unsigned bsBase = (unsigned)(uintptr_t)(void*)(&Bs[0]);
    unsigned btr[4];
    #pragma unroll
    for (int ni = 0; ni < 4; ++ni)
        btr[ni] = bsBase + (unsigned)((2 * lk) * 1024 + ((wn >> 4) + ni) * 128 + l15 * 2);

    f32x4 acc[4][4];
    #pragma unroll
    for (int mi = 0; mi < 4; ++mi)
        #pragma unroll
        for (int ni = 0; ni < 4; ++ni) acc[mi][ni] = f32x4{0.f, 0.f, 0.f, 0.f};

    auto LOADA = [&](f32x4* av, int ks) {
        const int kgs = k0 + ks * 32;
        const float* ap;
        if (CROP) {
            // crop: k-chunk p of 4608 is contiguous at c*46080 + t*9216 + 4608
            const int p = kgs / 4608;
            const int j = kgs - p * 4608;
            const int c = p % 3, t9 = p / 3;
            ap = abase + c * 46080 + t9 * 9216 + 4608 + j + a_off;
        } else {
            ap = abase + kgs + a_off;
        }
        #pragma unroll
        for (int i = 0; i < 4; ++i) av[i] = *(const f32x4*)(ap + 4 * i);
    };
    auto LOADB = [&](f32x4* bv, int ks) {
        const float* bp = bbase + (size_t)(k0 + ks * 32) * 512;
        #pragma unroll
        for (int i = 0; i < 4; ++i) bv[i] = *(const f32x4*)(bp + 4 * i);
    };
    auto PACK = [&](const f32x4* av, const f32x4* bv) {
        uint4 pa0, pa1, pb0, pb1;
        pa0.x = pk2(av[0].x, av[0].y); pa0.y = pk2(av[0].z, av[0].w);
        pa0.z = pk2(av[1].x, av[1].y); pa0.w = pk2(av[1].z, av[1].w);
        pa1.x = pk2(av[2].x, av[2].y); pa1.y = pk2(av[2].z, av[2].w);
        pa1.z = pk2(av[3].x, av[3].y); pa1.w = pk2(av[3].z, av[3].w);
        As[a_u0] = pa0;
        As[a_u1] = pa1;
        pb0.x = pk2(bv[0].x, bv[0].y); pb0.y = pk2(bv[0].z, bv[0].w);
        pb0.z = pk2(bv[1].x, bv[1].y); pb0.w = pk2(bv[1].z, bv[1].w);
        pb1.x = pk2(bv[2].x, bv[2].y); pb1.y = pk2(bv[2].z, bv[2].w);
        pb1.z = pk2(bv[3].x, bv[3].y); pb1.w = pk2(bv[3].z, bv[3].w);
        Bs[b_u0]     = pb0;   // cols 16g..+7   (h=0)
        Bs[b_u0 + 1] = pb1;   // cols 16g+8..+15 (h=1)
    };
    auto COMPUTE = [&]() {
        bf16x8 af[4];
        #pragma unroll
        for (int mi = 0; mi < 4; ++mi) af[mi] = __builtin_bit_cast(bf16x8, As[ua[mi]]);
        u32x2 lo[4], hi[4];
        #pragma unroll
        for (int ni = 0; ni < 4; ++ni) { lo[ni] = tr_lo(btr[ni]); hi[ni] = tr_hi(btr[ni]); }
        asm volatile("s_waitcnt lgkmcnt(0)" ::: "memory");
        __builtin_amdgcn_sched_barrier(0);
        bf16x8 bf[4];
        #pragma unroll
        for (int ni = 0; ni < 4; ++ni) {
            uint4 q; q.x = lo[ni].x; q.y = lo[ni].y; q.z = hi[ni].x; q.w = hi[ni].y;
            bf[ni] = __builtin_bit_cast(bf16x8, q);
        }
        #pragma unroll
        for (int mi = 0; mi < 4; ++mi)
            #pragma unroll
            for (int ni = 0; ni < 4; ++ni)
                acc[mi][ni] = __builtin_amdgcn_mfma_f32_16x16x32_bf16(af[mi], bf[ni], acc[mi][ni], 0, 0, 0);
    };

    // ---- 2-deep ping-pong pipeline (ksteps is even: 48 / 20)
    f32x4 av0[4], bv0[4], av1[4], bv1[4];
    LOADA(av0, 0); LOADB(bv0, 0);
    for (int ks = 0; ks < ksteps; ks += 2) {
        LOADA(av1, ks + 1); LOADB(bv1, ks + 1);
        PACK(av0, bv0);
        __syncthreads();
        COMPUTE();
        __syncthreads();
        if (ks + 2 < ksteps) { LOADA(av0, ks + 2); LOADB(bv0, ks + 2); }
        PACK(av1, bv1);
        __syncthreads();
        COMPUTE();
        __syncthreads();
    }

    // ---- epilogue: fp32 partials. C/D: col = lane&15, row = (lane>>4)*4+r
    #pragma unroll
    for (int mi = 0; mi < 4; ++mi)
        #pragma unroll
        for (int ni = 0; ni < 4; ++ni) {
            const int col = n0 + wn + ni * 16 + l15;
            #pragma unroll
            for (int r = 0; r < 4; ++r) {
                const int row = m0 + wm + mi * 16 + lk * 4 + r;
                part[(size_t)row * 512 + col] = acc[mi][ni][r];
            }
        }
}

// ---------- reduce split-K partials + row L2 normalization ----------
__global__ __launch_bounds__(256) void norm_kernel(
    const float* __restrict__ partA, const float* __restrict__ partV,
    float* __restrict__ Aout, float* __restrict__ Vout, int nzV)
{
    const int row = blockIdx.x;          // 0..1023
    const int tid = threadIdx.x;
    const bool isV = row >= 512;
    const int r = isV ? (row - 512) : row;
    const int c0 = tid, c1 = tid + 256;

    float v0 = 0.f, v1 = 0.f;
    if (isV) {
        for (int zz = 0; zz < nzV; ++zz) {
            const float* p = partV + (size_t)zz * 262144 + (size_t)r * 512;
            v0 += p[c0]; v1 += p[c1];
        }
    } else {
        #pragma unroll
        for (int zz = 0; zz < KSA; ++zz) {
            const float* p = partA + (size_t)zz * 262144 + (size_t)r * 512;
            v0 += p[c0]; v1 += p[c1];
        }
    }

    float ss = v0 * v0 + v1 * v1;
    #pragma unroll
    for (int off = 32; off > 0; off >>= 1) ss += __shfl_down(ss, off);
    __shared__ float sbuf[4];
    if ((tid & 63) == 0) sbuf[tid >> 6] = ss;
    __syncthreads();
    const float total = sbuf[0] + sbuf[1] + sbuf[2] + sbuf[3];
    const float inv = 1.f / fmaxf(sqrtf(total), 1e-12f);

    float* outp = (isV ? Vout : Aout) + (size_t)r * 512;
    outp[c0] = v0 * inv;
    outp[c1] = v1 * inv;
}

// ---------------------------------------------------------------------------
// similarity: S = Anorm . Vnorm^T (64x64 tiles, f32 in, bf16 MFMA),
// epilogue: den[row&255] += sum_col exp(S); diag-family exp -> num[row&255]
// ---------------------------------------------------------------------------
__global__ __launch_bounds__(256) void sim_kernel(
    const float* __restrict__ A, const float* __restrict__ V,
    float* __restrict__ den, float* __restrict__ num)
{
    __shared__ uint4 As[2][256];
    __shared__ uint4 Bs[2][256];

    const int tid = threadIdx.x;
    const int m0 = (blockIdx.x >> 3) * 64;
    const int n0 = (blockIdx.x & 7) * 64;
    const int nsteps = 16;               // K = 512

    const int a_row = tid >> 2, a_kb = tid & 3;
    const int b_col = tid & 63, b_kb = tid >> 6;
    const int a_u = (a_kb * 64 + a_row) ^ (a_kb << 1);
    const int b_u = (b_kb * 64 + b_col) ^ (b_kb << 1);

    const float* abase = A + (size_t)(m0 + a_row) * 512;
    const float* bptr  = V + (size_t)(n0 + b_col) * 512 + b_kb * 8;
    int aoff = a_kb * 8;

    const int lane = tid & 63, wid = tid >> 6;
    const int wrow = (wid >> 1) * 32, wcol = (wid & 1) * 32;
    const int l15 = lane & 15, lk = lane >> 4;

    int ra[2], rb[2];
    #pragma unroll
    for (int m = 0; m < 2; ++m) ra[m] = (lk * 64 + wrow + m * 16 + l15) ^ (lk << 1);
    #pragma unroll
    for (int n = 0; n < 2; ++n) rb[n] = (lk * 64 + wcol + n * 16 + l15) ^ (lk << 1);

    f32x4 acc[2][2];
    #pragma unroll
    for (int m = 0; m < 2; ++m)
        #pragma unroll
        for (int n = 0; n < 2; ++n) acc[m][n] = f32x4{0.f, 0.f, 0.f, 0.f};

    float4 A0 = *(const float4*)(abase + aoff);
    float4 A1 = *(const float4*)(abase + aoff + 4);
    float4 B0 = *(const float4*)bptr;
    float4 B1 = *(const float4*)(bptr + 4);

    for (int ks = 0; ks < nsteps; ++ks) {
        const int cur = ks & 1;
        const bool more = (ks + 1 < nsteps);
        float4 A0n, A1n, B0n, B1n;
        if (more) {
            aoff += 32; bptr += 32;
            A0n = *(const float4*)(abase + aoff);
            A1n = *(const float4*)(abase + aoff + 4);
            B0n = *(const float4*)bptr;
            B1n = *(const float4*)(bptr + 4);
        }
        uint4 pa;
        pa.x = pk2(A0.x, A0.y); pa.y = pk2(A0.z, A0.w);
        pa.z = pk2(A1.x, A1.y); pa.w = pk2(A1.z, A1.w);
        As[cur][a_u] = pa;
        uint4 pb;
        pb.x = pk2(B0.x, B0.y); pb.y = pk2(B0.z, B0.w);
        pb.z = pk2(B1.x, B1.y); pb.w = pk2(B1.z, B1.w);
        Bs[cur][b_u] = pb;
        __syncthreads();

        bf16x8 af[2], bfr[2];
        #pragma unroll
        for (int m = 0; m < 2; ++m) af[m] = __builtin_bit_cast(bf16x8, As[cur][ra[m]]);
        #pragma unroll
        for (int n = 0; n < 2; ++n) bfr[n] = __builtin_bit_cast(bf16x8, Bs[cur][rb[n]]);
        #pragma unroll
        for (int m = 0; m < 2; ++m)
            #pragma unroll
            for (int n = 0; n < 2; ++n)
                acc[m][n] = __builtin_amdgcn_mfma_f32_16x16x32_bf16(af[m], bfr[n], acc[m][n], 0, 0, 0);

        if (more) { A0 = A0n; A1 = A1n; B0 = B0n; B1 = B1n; }
    }

    #pragma unroll
    for (int m = 0; m < 2; ++m) {
        float rs[4] = {0.f, 0.f, 0.f, 0.f};
        #pragma unroll
        for (int n = 0; n < 2; ++n) {
            const int col = n0 + wcol + n * 16 + l15;
            #pragma unroll
            for (int r = 0; r < 4; ++r) {
                const int row = m0 + wrow + m * 16 + lk * 4 + r;
                const float e = __expf(acc[m][n][r]);
                rs[r] += e;
                if (((row - col) & 255) == 0) atomicAdd(num + (row & 255), e);
            }
        }
        #pragma unroll
        for (int r = 0; r < 4; ++r) {
            float v = rs[r];
            v += __shfl_xor(v, 1);
            v += __shfl_xor(v, 2);
            v += __shfl_xor(v, 4);
            v += __shfl_xor(v, 8);
            if (l15 == 0) {
                const int row = m0 + wrow + m * 16 + lk * 4 + r;
                atomicAdd(den + (row & 255), v);
            }
        }
    }
}

// ---------- zero den/num accumulators ----------
__global__ __launch_bounds__(512) void zero_kernel(float* __restrict__ p) {
    p[threadIdx.x] = 0.f;
}

// ---------- a1.a2 and v1.v2 dots -> num += exp(dot) ----------
__global__ __launch_bounds__(256) void dots_kernel(
    const float* __restrict__ A, const float* __restrict__ V,
    float* __restrict__ num)
{
    const int b = blockIdx.x;            // 0..511
    const int i = b & 255;
    const float* X = (b < 256) ? A : V;
    const float* x = X + (size_t)i * 512;
    const float* y = X + (size_t)(i + 256) * 512;
    const int tid = threadIdx.x;
    float d = x[tid] * y[tid] + x[tid + 256] * y[tid + 256];
    #pragma unroll
    for (int off = 32; off > 0; off >>= 1) d += __shfl_down(d, off);
    __shared__ float sbuf[4];
    if ((tid & 63) == 0) sbuf[tid >> 6] = d;
    __syncthreads();
    if (tid == 0) atomicAdd(num + i, __expf(sbuf[0] + sbuf[1] + sbuf[2] + sbuf[3]));
}

// ---------- final: loss = mean(log den - log num) ----------
__global__ __launch_bounds__(256) void final_kernel(
    const float* __restrict__ den, const float* __restrict__ num,
    float* __restrict__ out)
{
    const int tid = threadIdx.x;
    float v = logf(den[tid]) - logf(num[tid]);
    #pragma unroll
    for (int off = 32; off > 0; off >>= 1) v += __shfl_down(v, off);
    __shared__ float sbuf[4];
    if ((tid & 63) == 0) sbuf[tid >> 6] = v;
    __syncthreads();
    if (tid == 0) out[0] = (sbuf[0] + sbuf[1] + sbuf[2] + sbuf[3]) * (1.f / 256.f);
}

// ---------- launch ----------
extern "C" void kernel_launch(void* const* d_in, const int* in_sizes, int n_in,
                              void* d_out, int out_size, void* d_ws, size_t ws_size,
                              hipStream_t stream)
{
    (void)in_sizes; (void)n_in; (void)out_size; (void)ws_size;
    const float* a_1 = (const float*)d_in[0];
    const float* v_1 = (const float*)d_in[1];
    const float* a_2 = (const float*)d_in[2];
    const float* v_2 = (const float*)d_in[3];
    const float* W_a = (const float*)d_in[4];
    const float* W_v = (const float*)d_in[5];
    float* out = (float*)d_out;

    float* cur   = (float*)d_ws;
    float* den   = cur; cur += 256;
    float* num   = cur; cur += 256;
    float* Anorm = cur; cur += 262144;
    float* Vnorm = cur; cur += 262144;
    float* partA = cur; cur += (size_t)KSA * 262144;
    float* partV = cur; cur += (size_t)KSV * 262144;   // ~51 MB total

    zero_kernel<<<1, 512, 0, stream>>>(den);   // zeros den[256]+num[256]

    gemm_kernel<1><<<16 * KSV, 256, 0, stream>>>(v_1, v_2, W_v, partV, 48);
    gemm_kernel<0><<<16 * KSA, 256, 0, stream>>>(a_1, a_2, W_a, partA, 20);

    norm_kernel<<<1024, 256, 0, stream>>>(partA, partV, Anorm, Vnorm, KSV);
    sim_kernel<<<64, 256, 0, stream>>>(Anorm, Vnorm, den, num);
    dots_kernel<<<512, 256, 0, stream>>>(Anorm, Vnorm, num);
    final_kernel<<<1, 256, 0, stream>>>(den, num, out);
}